// Round 12
// baseline (113.584 us; speedup 1.0000x reference)
//
#include <hip/hip_runtime.h>

// out[b,o] = sum_i silu(x)*BW + ((xs^2-1)*exp(-xs^2/2))*WW + bias,  xs=(x-T)/S
// ROUND 18 == ROUND 17 resubmitted verbatim (R17 bench died in the broker:
// "MI355X container failed twice" -- no compile/correctness/counter data).
// Synthesis of proven pieces -- R9's 8x4 tile (BT=128/OT=64, VGPR 120
// spill-free under (256,2)) + R13 Horner (-32 transient regs vs R9)
// + R10 lout alias (LDS 38.4KB -> 4 blocks/CU) + R16 KS=16 (grid 8x8x16 =
// 1024 -> 4 blocks/CU, ws path verified).  R16 post-mortem: convoy theory
// dead (KS=16 alone: +3.4us).  Correct LDS accounting: ds_read_b128 costs
// the LDS pipe ~8-12cyc ISSUE regardless of broadcast; R13 = 5120 instr/CU
// ~= 17-26us vs VALU 29us -- co-bottleneck.  8x4 tile: 24 reads per 128
// contributions (vs R13's 20 per 64) = -40% LDS-pipe pressure at EQUAL
// occupancy (R14's mistake was shrinking occupancy to get this).
// Wavelet math verified since round 2:
//   a2 = C2/s^2, m1 = -2*a2*t, m2' = a2*t^2 - C2, q = w * 2^C2 / C2
//   p = (a2*x + m1)*x + m2';  contribution = p * q * 2^p,  C2 = -0.5*log2(e)

constexpr int IN_F  = 512;
constexpr int OUT_F = 512;
constexpr int BATCH = 1024;
constexpr int BT = 128, OT = 64;    // block tile, 8x4 acc/thread
constexpr int IT = 16;              // k chunk in LDS
constexpr int PITCH = IT + 4;       // f32 rows: 16B-aligned, 2-way banks (free)
constexpr int HP = IT + 4;          // f16 rows: 40B stride, conflict-free b64
constexpr int LP = OT + 1;          // epilogue merge pitch (128 x 65)
constexpr int BO  = BATCH * OUT_F;  // 524288

#define LOG2E 1.44269504088897f
#define C2f   (-0.72134752044448f)
#define NC2f  ( 0.72134752044448f)
#define RQf   (-0.84083003f)   /* 2^C2 / C2 = e^{-1/2}/C2 */

typedef float v2f   __attribute__((ext_vector_type(2)));
typedef float f32x4 __attribute__((ext_vector_type(4)));
typedef _Float16 half4 __attribute__((ext_vector_type(4)));

__device__ __forceinline__ float fexp2(float v) { return __builtin_amdgcn_exp2f(v); }
__device__ __forceinline__ float frcp(float v)  { return __builtin_amdgcn_rcpf(v); }
__device__ __forceinline__ v2f pkfma(v2f a, v2f b, v2f c) {
  return __builtin_elementwise_fma(a, b, c);
}
__device__ __forceinline__ float fsilu(float v) {
  return v * frcp(1.f + fexp2(v * -LOG2E));
}

// LDS carve (float offsets):
//   lx [    0..2559]  x f32 128x20
//   la [ 2560..3839]  lm [3840..5119]  ln [5120..6399]  lq [6400..7679] (64x20)
//   hx [ 7680..8959]  silu(x) f16 128x20 (MFMA A)
//   hb [ 8960..9599]  basew   f16  64x20 (MFMA B)
//   lout [  0..8319]  ALIAS: epilogue merge 128x65 (after barrier)
constexpr int SMEM_F = 9600;        // 38400 B; 4 blocks/CU = 153.6KB

template<int KS>
__global__ __launch_bounds__(256, 2)
void wkan_main(const float* __restrict__ x, const float* __restrict__ basew,
               const float* __restrict__ wavew, const float* __restrict__ scale,
               const float* __restrict__ transl, const float* __restrict__ bias,
               float* __restrict__ partial, float* __restrict__ out, int use_ws)
{
  constexpr int KR  = IN_F / KS;    // k per block (32 at KS=16)
  constexpr int NCH = KR / IT;      // chunks (2 at KS=16)

  __shared__ float smem[SMEM_F];
  float* lx = smem;
  float* la = smem + 2560;
  float* lm = smem + 3840;
  float* ln = smem + 5120;
  float* lq = smem + 6400;
  _Float16* hx = (_Float16*)(smem + 7680);
  _Float16* hb = (_Float16*)(smem + 8960);
  float* lout = smem;               // epilogue alias

  const int tid = threadIdx.x;
  const int b0 = blockIdx.x * BT;
  const int o0 = blockIdx.y * OT;
  const int ks = blockIdx.z;
  const int k0 = ks * KR;

  const int srow = tid >> 2;        // 0..63 staging row
  const int sc4  = (tid & 3) * 4;   // 0,4,8,12
  const int lofs = srow * PITCH + sc4;
  const int hofs = srow * HP + sc4;

  const int to = tid & 15;          // output col group (cols to + 16c, c<4)
  const int tb = tid >> 4;          // output row group 0..15 (rows tb + 16r, r<8)

  const int lane = tid & 63;
  const int wid  = tid >> 6;        // wave 0..3 -> m-tiles 2wid, 2wid+1
  const int frow = lane & 15;       // m/n within MFMA tile
  const int kgrp = (lane >> 4) * 4; // k group within chunk

  v2f zz; zz.x = 0.f; zz.y = 0.f;
  v2f acc[8][4];
#pragma unroll
  for (int r = 0; r < 8; ++r)
#pragma unroll
    for (int c = 0; c < 4; ++c) acc[r][c] = zz;

  f32x4 accb[2][4];                 // base fragments: 2 m-tiles x 4 n-tiles
#pragma unroll
  for (int mt = 0; mt < 2; ++mt)
#pragma unroll
    for (int nt = 0; nt < 4; ++nt) accb[mt][nt] = (f32x4)0.f;

  for (int kc = 0; kc < NCH; ++kc) {
    const int g = k0 + kc * IT + sc4;
    if (kc) __syncthreads();          // prev-chunk readers done
    // ---------- stage chunk ----------
    {
      float4 xv0 = *(const float4*)(x + (size_t)(b0 + srow)      * IN_F + g);
      float4 xv1 = *(const float4*)(x + (size_t)(b0 + srow + 64) * IN_F + g);
      float4 sx0, sx1;
      sx0.x = fsilu(xv0.x); sx0.y = fsilu(xv0.y); sx0.z = fsilu(xv0.z); sx0.w = fsilu(xv0.w);
      sx1.x = fsilu(xv1.x); sx1.y = fsilu(xv1.y); sx1.z = fsilu(xv1.z); sx1.w = fsilu(xv1.w);
      *(float4*)(lx + lofs) = xv0;
      *(float4*)(lx + lofs + 64 * PITCH) = xv1;
      half4 h0, h1;
      h0[0] = (_Float16)sx0.x; h0[1] = (_Float16)sx0.y;
      h0[2] = (_Float16)sx0.z; h0[3] = (_Float16)sx0.w;
      h1[0] = (_Float16)sx1.x; h1[1] = (_Float16)sx1.y;
      h1[2] = (_Float16)sx1.z; h1[3] = (_Float16)sx1.w;
      *(half4*)(hx + hofs) = h0;
      *(half4*)(hx + hofs + 64 * HP) = h1;

      float4 sv = *(const float4*)(scale  + (size_t)(o0 + srow) * IN_F + g);
      float4 tv = *(const float4*)(transl + (size_t)(o0 + srow) * IN_F + g);
      float4 av, mv, nv;
      {
        float a2, a2t;
        a2 = C2f * frcp(sv.x * sv.x); a2t = a2 * tv.x;
        av.x = a2; mv.x = -2.f * a2t; nv.x = fmaf(a2t, tv.x, NC2f);
        a2 = C2f * frcp(sv.y * sv.y); a2t = a2 * tv.y;
        av.y = a2; mv.y = -2.f * a2t; nv.y = fmaf(a2t, tv.y, NC2f);
        a2 = C2f * frcp(sv.z * sv.z); a2t = a2 * tv.z;
        av.z = a2; mv.z = -2.f * a2t; nv.z = fmaf(a2t, tv.z, NC2f);
        a2 = C2f * frcp(sv.w * sv.w); a2t = a2 * tv.w;
        av.w = a2; mv.w = -2.f * a2t; nv.w = fmaf(a2t, tv.w, NC2f);
      }
      *(float4*)(la + lofs) = av;
      *(float4*)(lm + lofs) = mv;
      *(float4*)(ln + lofs) = nv;

      float4 wv = *(const float4*)(wavew + (size_t)(o0 + srow) * IN_F + g);
      float4 qv;
      qv.x = wv.x * RQf; qv.y = wv.y * RQf; qv.z = wv.z * RQf; qv.w = wv.w * RQf;
      *(float4*)(lq + lofs) = qv;

      float4 bv = *(const float4*)(basew + (size_t)(o0 + srow) * IN_F + g);
      half4 hbv;
      hbv[0] = (_Float16)bv.x; hbv[1] = (_Float16)bv.y;
      hbv[2] = (_Float16)bv.z; hbv[3] = (_Float16)bv.w;
      *(half4*)(hb + hofs) = hbv;
    }
    __syncthreads();                  // chunk kc ready in LDS

    // ---------- base branch: 8 MFMA per wave on the matrix pipe ----------
    {
      half4 af0 = *(const half4*)(hx + (wid * 32 +      frow) * HP + kgrp);
      half4 af1 = *(const half4*)(hx + (wid * 32 + 16 + frow) * HP + kgrp);
#pragma unroll
      for (int nt = 0; nt < 4; ++nt) {
        half4 bf = *(const half4*)(hb + (nt * 16 + frow) * HP + kgrp);
        accb[0][nt] = __builtin_amdgcn_mfma_f32_16x16x16f16(af0, bf, accb[0][nt], 0, 0, 0);
        accb[1][nt] = __builtin_amdgcn_mfma_f32_16x16x16f16(af1, bf, accb[1][nt], 0, 0, 0);
      }
    }

    // ---------- wavelet: 8x4 outputs/thread on the VALU (Horner) ----------
    for (int ii = 0; ii < IT; ii += 4) {
      float4 xr[8];
#pragma unroll
      for (int r = 0; r < 8; ++r) {
        const int row = (tb + 16 * r) * PITCH + ii;
        xr[r] = *(const float4*)(lx + row);
      }
#pragma unroll
      for (int c = 0; c < 4; ++c) {
        const int orow = (to + 16 * c) * PITCH + ii;
        float4 A = *(const float4*)(la + orow);
        float4 M = *(const float4*)(lm + orow);
        float4 N = *(const float4*)(ln + orow);
        float4 Q = *(const float4*)(lq + orow);
        v2f Al = {A.x, A.y}, Ah = {A.z, A.w};
        v2f Ml = {M.x, M.y}, Mh = {M.z, M.w};
        v2f Nl = {N.x, N.y}, Nh = {N.z, N.w};
        v2f Ql = {Q.x, Q.y}, Qh = {Q.z, Q.w};
#pragma unroll
        for (int r = 0; r < 8; ++r) {
          v2f xl  = {xr[r].x, xr[r].y}, xh  = {xr[r].z, xr[r].w};
          v2f p, e, gg;
          p = pkfma(pkfma(Al, xl, Ml), xl, Nl);
          e.x = fexp2(p.x); e.y = fexp2(p.y);
          gg = p * Ql;
          acc[r][c] = pkfma(gg, e, acc[r][c]);
          p = pkfma(pkfma(Ah, xh, Mh), xh, Nh);
          e.x = fexp2(p.x); e.y = fexp2(p.y);
          gg = p * Qh;
          acc[r][c] = pkfma(gg, e, acc[r][c]);
        }
      }
    }
  }

  // ---------- epilogue: merge base fragments with wavelet acc ----------
  __syncthreads();                  // all LDS tile reads done; lout may alias
  // D layout: n = lane&15, m = (lane>>4)*4 + i   (within each 16x16 tile)
#pragma unroll
  for (int mt = 0; mt < 2; ++mt)
#pragma unroll
    for (int nt = 0; nt < 4; ++nt)
#pragma unroll
      for (int i = 0; i < 4; ++i)
        lout[(wid * 32 + mt * 16 + (lane >> 4) * 4 + i) * LP + nt * 16 + frow]
            = accb[mt][nt][i];
  __syncthreads();

#pragma unroll
  for (int r = 0; r < 8; ++r) {
    const int br = b0 + tb + 16 * r;
#pragma unroll
    for (int c = 0; c < 4; ++c) {
      const int oc = o0 + to + 16 * c;
      float res = acc[r][c].x + acc[r][c].y
                + lout[(tb + 16 * r) * LP + to + 16 * c];
      if (use_ws) {
        partial[(size_t)ks * BO + (size_t)br * OUT_F + oc] = res;
      } else {
        if (ks == 0) res += bias[oc];
        atomicAdd(out + (size_t)br * OUT_F + oc, res);
      }
    }
  }
}

template<int KS>
__global__ __launch_bounds__(256)
void wkan_reduce(const float* __restrict__ partial, const float* __restrict__ bias,
                 float* __restrict__ out)
{
  const int i4 = (blockIdx.x * 256 + threadIdx.x) * 4;
  float4 r = *(const float4*)(bias + (i4 & (OUT_F - 1)));
#pragma unroll
  for (int k = 0; k < KS; ++k) {
    float4 a = *(const float4*)(partial + (size_t)k * BO + i4);
    r.x += a.x; r.y += a.y; r.z += a.z; r.w += a.w;
  }
  *(float4*)(out + i4) = r;
}

extern "C" void kernel_launch(void* const* d_in, const int* in_sizes, int n_in,
                              void* d_out, int out_size, void* d_ws, size_t ws_size,
                              hipStream_t stream) {
  const float* x  = (const float*)d_in[0];
  const float* bw = (const float*)d_in[1];
  const float* ww = (const float*)d_in[2];
  const float* sc = (const float*)d_in[3];
  const float* tr = (const float*)d_in[4];
  const float* bi = (const float*)d_in[5];
  float* out = (float*)d_out;

  if (ws_size >= (size_t)16 * BO * sizeof(float)) {
    // KS=16: grid 8x8x16 = 1024 blocks = 4 blocks/CU (verified path in R16)
    dim3 grid(BATCH / BT, OUT_F / OT, 16);
    wkan_main<16><<<grid, dim3(256), 0, stream>>>(x, bw, ww, sc, tr, bi,
                                                  (float*)d_ws, out, 1);
    wkan_reduce<16><<<dim3(BO / 1024), dim3(256), 0, stream>>>((const float*)d_ws, bi, out);
  } else if (ws_size >= (size_t)8 * BO * sizeof(float)) {
    // KS=8: grid 8x8x8 = 512 (R9-like occupancy; safe fallback)
    dim3 grid(BATCH / BT, OUT_F / OT, 8);
    wkan_main<8><<<grid, dim3(256), 0, stream>>>(x, bw, ww, sc, tr, bi,
                                                 (float*)d_ws, out, 1);
    wkan_reduce<8><<<dim3(BO / 1024), dim3(256), 0, stream>>>((const float*)d_ws, bi, out);
  } else {
    hipMemsetAsync(d_out, 0, (size_t)out_size * sizeof(float), stream);
    dim3 grid(BATCH / BT, OUT_F / OT, 8);
    wkan_main<8><<<grid, dim3(256), 0, stream>>>(x, bw, ww, sc, tr, bi,
                                                 (float*)d_ws, out, 0);
  }
}

// Round 13
// 110.898 us; speedup vs baseline: 1.0242x; 1.0242x over previous
//
#include <hip/hip_runtime.h>

// out[b,o] = sum_i silu(x)*BW + ((xs^2-1)*exp(-xs^2/2))*WW + bias,  xs=(x-T)/S
// ROUND 19: R13 base (best, 48.4us) + software-pipelined compute loop.
// R18 post-mortem: 3rd experiment (R7/R14/R18) where cutting LDS-read COUNT
// bought nothing.  Triangulation: VALU busy 29us + LDS pipe 25.6us ~= dur
// 48.4 => the pipes run ~serialized.  Cause: identical instruction streams
// -> after each barrier all 16 waves burst 20 ds_read_b128, all wait
// lgkmcnt, all compute; round-robin LDS pipe keeps waves lockstepped
// (CU-wide read/compute convoy).  At VGPR=64 the compiler CANNOT hoist next
// reads over current compute.  Fix: flatten (ii,c) -> 16 stages/chunk;
// stage s issues s+1's 4 param reads (+4 x reads at ii boundary) BEFORE
// computing s from registers loaded a stage ago.  Forced prefetch regs
// (~+40 -> ~105 working set) jump the allocator to the 128 step (R9/R18
// precedent: 120/88 clean).  All else R13 verbatim.
// Wavelet math verified since round 2:
//   a2 = C2/s^2, m1 = -2*a2*t, m2' = a2*t^2 - C2, q = w * 2^C2 / C2
//   p = (a2*x + m1)*x + m2';  contribution = p * q * 2^p,  C2 = -0.5*log2(e)

constexpr int IN_F  = 512;
constexpr int OUT_F = 512;
constexpr int BATCH = 1024;
constexpr int BT = 64, OT = 64;     // block tile
constexpr int KS = 8;               // k-split -> grid 16x8x8 = 1024 blocks
constexpr int KR = IN_F / KS;       // 64 k per block
constexpr int IT = 16;              // k chunk in LDS
constexpr int PITCH = IT + 4;       // f32 rows: 16B-aligned, 2-way banks (free)
constexpr int HP = IT + 4;          // f16 rows: 40B stride, conflict-free b64
constexpr int LP = OT + 1;          // epilogue merge pitch
constexpr int NCH = KR / IT;        // 4 chunks
constexpr int BO  = BATCH * OUT_F;  // 524288

#define LOG2E 1.44269504088897f
#define C2f   (-0.72134752044448f)
#define NC2f  ( 0.72134752044448f)
#define RQf   (-0.84083003f)   /* 2^C2 / C2 = e^{-1/2}/C2 */

typedef float v2f   __attribute__((ext_vector_type(2)));
typedef float f32x4 __attribute__((ext_vector_type(4)));
typedef _Float16 half4 __attribute__((ext_vector_type(4)));

__device__ __forceinline__ float fexp2(float v) { return __builtin_amdgcn_exp2f(v); }
__device__ __forceinline__ float frcp(float v)  { return __builtin_amdgcn_rcpf(v); }
__device__ __forceinline__ v2f pkfma(v2f a, v2f b, v2f c) {
  return __builtin_elementwise_fma(a, b, c);
}
__device__ __forceinline__ float fsilu(float v) {
  return v * frcp(1.f + fexp2(v * -LOG2E));
}

// LDS carve (floats) -- identical to R13:
//   lx   [   0..1279]  x tile, f32, 64x20
//   la   [1280..2559]  lm [2560..3839]  ln [3840..5119]  lq [5120..6399]
//   hx   [6400..7039]  silu(x) f16 64x20 (MFMA A)
//   hb   [7040..7679]  basew   f16 64x20 (MFMA B)
//   lout [   0..4159]  ALIAS: epilogue merge 64x65 (after barrier)
constexpr int SMEM_F = 7680;        // 30720 B

__global__ __launch_bounds__(256, 2)
void wkan_main(const float* __restrict__ x, const float* __restrict__ basew,
               const float* __restrict__ wavew, const float* __restrict__ scale,
               const float* __restrict__ transl, const float* __restrict__ bias,
               float* __restrict__ partial, float* __restrict__ out, int use_ws)
{
  __shared__ float smem[SMEM_F];
  float* lx = smem;
  float* la = smem + 1280;
  float* lm = smem + 2560;
  float* ln = smem + 3840;
  float* lq = smem + 5120;
  _Float16* hx = (_Float16*)(smem + 6400);
  _Float16* hb = (_Float16*)(smem + 7040);
  float* lout = smem;               // epilogue alias

  const int tid = threadIdx.x;
  const int b0 = blockIdx.x * BT;
  const int o0 = blockIdx.y * OT;
  const int ks = blockIdx.z;
  const int k0 = ks * KR;

  const int srow = tid >> 2;        // 0..63 staging row
  const int sc4  = (tid & 3) * 4;   // 0,4,8,12
  const int lofs = srow * PITCH + sc4;
  const int hofs = srow * HP + sc4;

  const int to = tid & 15;          // output col group (cols to + 16c)
  const int tb = tid >> 4;          // output row group 0..15 (rows tb + 16r)

  const int lane = tid & 63;
  const int wid  = tid >> 6;        // wave 0..3 -> m-tile wid
  const int frow = lane & 15;       // m/n within MFMA tile
  const int kgrp = (lane >> 4) * 4; // k group within chunk

  v2f zz; zz.x = 0.f; zz.y = 0.f;
  v2f acc[4][4];
#pragma unroll
  for (int r = 0; r < 4; ++r)
#pragma unroll
    for (int c = 0; c < 4; ++c) acc[r][c] = zz;

  f32x4 accb[4];                    // base-GEMM fragments: 4 n-tiles
#pragma unroll
  for (int nt = 0; nt < 4; ++nt) accb[nt] = (f32x4)0.f;

  for (int kc = 0; kc < NCH; ++kc) {
    const int g = k0 + kc * IT + sc4;
    if (kc) __syncthreads();          // prev-chunk readers done
    // ---------- stage chunk (R13 verbatim) ----------
    {
      float4 xv = *(const float4*)(x + (size_t)(b0 + srow) * IN_F + g);
      float4 sx;
      sx.x = fsilu(xv.x); sx.y = fsilu(xv.y); sx.z = fsilu(xv.z); sx.w = fsilu(xv.w);
      *(float4*)(lx + lofs) = xv;
      half4 h0;
      h0[0] = (_Float16)sx.x; h0[1] = (_Float16)sx.y;
      h0[2] = (_Float16)sx.z; h0[3] = (_Float16)sx.w;
      *(half4*)(hx + hofs) = h0;

      float4 sv = *(const float4*)(scale  + (size_t)(o0 + srow) * IN_F + g);
      float4 tv = *(const float4*)(transl + (size_t)(o0 + srow) * IN_F + g);
      float4 av, mv, nv;
      {
        float a2, a2t;
        a2 = C2f * frcp(sv.x * sv.x); a2t = a2 * tv.x;
        av.x = a2; mv.x = -2.f * a2t; nv.x = fmaf(a2t, tv.x, NC2f);
        a2 = C2f * frcp(sv.y * sv.y); a2t = a2 * tv.y;
        av.y = a2; mv.y = -2.f * a2t; nv.y = fmaf(a2t, tv.y, NC2f);
        a2 = C2f * frcp(sv.z * sv.z); a2t = a2 * tv.z;
        av.z = a2; mv.z = -2.f * a2t; nv.z = fmaf(a2t, tv.z, NC2f);
        a2 = C2f * frcp(sv.w * sv.w); a2t = a2 * tv.w;
        av.w = a2; mv.w = -2.f * a2t; nv.w = fmaf(a2t, tv.w, NC2f);
      }
      *(float4*)(la + lofs) = av;
      *(float4*)(lm + lofs) = mv;
      *(float4*)(ln + lofs) = nv;

      float4 wv = *(const float4*)(wavew + (size_t)(o0 + srow) * IN_F + g);
      float4 qv;
      qv.x = wv.x * RQf; qv.y = wv.y * RQf; qv.z = wv.z * RQf; qv.w = wv.w * RQf;
      *(float4*)(lq + lofs) = qv;

      float4 bv = *(const float4*)(basew + (size_t)(o0 + srow) * IN_F + g);
      half4 hbv;
      hbv[0] = (_Float16)bv.x; hbv[1] = (_Float16)bv.y;
      hbv[2] = (_Float16)bv.z; hbv[3] = (_Float16)bv.w;
      *(half4*)(hb + hofs) = hbv;
    }
    __syncthreads();                  // chunk kc ready in LDS

    // ---------- base branch: 4 MFMA on the matrix pipe ----------
    {
      half4 af = *(const half4*)(hx + (wid * 16 + frow) * HP + kgrp);
#pragma unroll
      for (int nt = 0; nt < 4; ++nt) {
        half4 bf = *(const half4*)(hb + (nt * 16 + frow) * HP + kgrp);
        accb[nt] = __builtin_amdgcn_mfma_f32_16x16x16f16(af, bf, accb[nt], 0, 0, 0);
      }
    }

    // ---------- wavelet: software-pipelined 16 stages (s = ii*4 + c) ------
    {
      float4 xrA[4], PA[4];
#pragma unroll
      for (int r = 0; r < 4; ++r)
        xrA[r] = *(const float4*)(lx + (tb + 16 * r) * PITCH);
      {
        const int orow = to * PITCH;          // c=0, ii=0
        PA[0] = *(const float4*)(la + orow);
        PA[1] = *(const float4*)(lm + orow);
        PA[2] = *(const float4*)(ln + orow);
        PA[3] = *(const float4*)(lq + orow);
      }
#pragma unroll
      for (int s = 0; s < 16; ++s) {
        const int c = s & 3;
        // ---- issue next stage's reads BEFORE computing this stage ----
        float4 PB[4], xrB[4];
        if (s + 1 < 16) {
          const int cn  = (s + 1) & 3;
          const int iin = ((s + 1) >> 2) * 4;
          const int orow = (to + 16 * cn) * PITCH + iin;
          PB[0] = *(const float4*)(la + orow);
          PB[1] = *(const float4*)(lm + orow);
          PB[2] = *(const float4*)(ln + orow);
          PB[3] = *(const float4*)(lq + orow);
          if (cn == 0) {
#pragma unroll
            for (int r = 0; r < 4; ++r)
              xrB[r] = *(const float4*)(lx + (tb + 16 * r) * PITCH + iin);
          }
        }
        // ---- compute stage s from registers loaded last stage ----
        v2f Al = {PA[0].x, PA[0].y}, Ah = {PA[0].z, PA[0].w};
        v2f Ml = {PA[1].x, PA[1].y}, Mh = {PA[1].z, PA[1].w};
        v2f Nl = {PA[2].x, PA[2].y}, Nh = {PA[2].z, PA[2].w};
        v2f Ql = {PA[3].x, PA[3].y}, Qh = {PA[3].z, PA[3].w};
#pragma unroll
        for (int r = 0; r < 4; ++r) {
          v2f xl = {xrA[r].x, xrA[r].y}, xh = {xrA[r].z, xrA[r].w};
          v2f p, e, gg;
          p = pkfma(pkfma(Al, xl, Ml), xl, Nl);
          e.x = fexp2(p.x); e.y = fexp2(p.y);
          gg = p * Ql;
          acc[r][c] = pkfma(gg, e, acc[r][c]);
          p = pkfma(pkfma(Ah, xh, Mh), xh, Nh);
          e.x = fexp2(p.x); e.y = fexp2(p.y);
          gg = p * Qh;
          acc[r][c] = pkfma(gg, e, acc[r][c]);
        }
        // ---- rotate pipeline registers ----
        if (s + 1 < 16) {
#pragma unroll
          for (int j = 0; j < 4; ++j) PA[j] = PB[j];
          if (((s + 1) & 3) == 0) {
#pragma unroll
            for (int r = 0; r < 4; ++r) xrA[r] = xrB[r];
          }
        }
      }
    }
  }

  // ---------- epilogue: merge base fragments with wavelet acc ----------
  __syncthreads();                  // all LDS tile reads done; lout may alias
  // D layout: n = lane&15, m = (lane>>4)*4 + i   (within each 16x16 tile)
#pragma unroll
  for (int nt = 0; nt < 4; ++nt)
#pragma unroll
    for (int i = 0; i < 4; ++i)
      lout[(wid * 16 + (lane >> 4) * 4 + i) * LP + nt * 16 + frow] = accb[nt][i];
  __syncthreads();

#pragma unroll
  for (int r = 0; r < 4; ++r) {
    const int br = b0 + tb + 16 * r;
#pragma unroll
    for (int c = 0; c < 4; ++c) {
      const int oc = o0 + to + 16 * c;
      float res = acc[r][c].x + acc[r][c].y
                + lout[(tb + 16 * r) * LP + to + 16 * c];
      if (use_ws) {
        partial[(size_t)ks * BO + (size_t)br * OUT_F + oc] = res;
      } else {
        if (ks == 0) res += bias[oc];
        atomicAdd(out + (size_t)br * OUT_F + oc, res);
      }
    }
  }
}

__global__ __launch_bounds__(256)
void wkan_reduce(const float* __restrict__ partial, const float* __restrict__ bias,
                 float* __restrict__ out)
{
  const int i4 = (blockIdx.x * 256 + threadIdx.x) * 4;
  float4 r = *(const float4*)(bias + (i4 & (OUT_F - 1)));
#pragma unroll
  for (int k = 0; k < KS; ++k) {
    float4 a = *(const float4*)(partial + (size_t)k * BO + i4);
    r.x += a.x; r.y += a.y; r.z += a.z; r.w += a.w;
  }
  *(float4*)(out + i4) = r;
}

extern "C" void kernel_launch(void* const* d_in, const int* in_sizes, int n_in,
                              void* d_out, int out_size, void* d_ws, size_t ws_size,
                              hipStream_t stream) {
  const float* x  = (const float*)d_in[0];
  const float* bw = (const float*)d_in[1];
  const float* ww = (const float*)d_in[2];
  const float* sc = (const float*)d_in[3];
  const float* tr = (const float*)d_in[4];
  const float* bi = (const float*)d_in[5];
  float* out = (float*)d_out;

  const int use_ws = ws_size >= (size_t)KS * BO * sizeof(float) ? 1 : 0;
  if (!use_ws) {
    hipMemsetAsync(d_out, 0, (size_t)out_size * sizeof(float), stream);
  }
  dim3 grid(BATCH / BT, OUT_F / OT, KS);  // 16 x 8 x 8 = 1024 blocks, 4/CU
  wkan_main<<<grid, dim3(256), 0, stream>>>(x, bw, ww, sc, tr, bi,
                                            (float*)d_ws, out, use_ws);
  if (use_ws) {
    wkan_reduce<<<dim3(BO / 1024), dim3(256), 0, stream>>>((const float*)d_ws, bi, out);
  }
}

// Round 14
// 108.274 us; speedup vs baseline: 1.0490x; 1.0242x over previous
//
#include <hip/hip_runtime.h>

// out[b,o] = sum_i silu(x)*BW + ((xs^2-1)*exp(-xs^2/2))*WW + bias,  xs=(x-T)/S
// ROUND 20 == ROUND 13 verbatim (session best: 48.4us main, VGPR 64, zero
// spill).  R19 post-mortem: hand software-pipeline allocated (VGPR 92, no
// spill) but regressed to 51.8us -- read/compute serialization is
// structural; pipelining cost occupancy headroom.  Ledger: every overlap
// lever (bigger tiles R7/R14/R17/R18, prefetch R8/R19, occupancy bounds
// R10-R12/R15, KS=16 R16) was neutral-to-worse; the only wins were
// instruction removals (R9 MFMA offload -5us, R13 Horner+clean-alloc -5us).
// Floor: VALU issue ~29us (2 pkfma + 2 quarter-rate exp2 per k-pair,
// algebraically minimal) + ~19us barrier-phased staging/LDS residue that 8
// structural variants could not overlap.  This is the practical roofline
// for this structure at source level.
//  (1) Horner:  p = (a2*x + m1)*x + m2'
//  (2) __launch_bounds__(256,2): the only bound that allocates without
//      spilling on this toolchain (R11/R12/R15 all hit the 64-reg step
//      with scratch traffic under tighter bounds).
//  (3) MFMA base branch (R9), lout epilogue alias (R10), KS=8 k-split.
// Wavelet math verified since round 2:
//   a2 = C2/s^2, m1 = -2*a2*t, m2' = a2*t^2 - C2, q = w * 2^C2 / C2
//   p = (a2*x + m1)*x + m2';  contribution = p * q * 2^p,  C2 = -0.5*log2(e)

constexpr int IN_F  = 512;
constexpr int OUT_F = 512;
constexpr int BATCH = 1024;
constexpr int BT = 64, OT = 64;     // block tile
constexpr int KS = 8;               // k-split -> grid 16x8x8 = 1024 blocks
constexpr int KR = IN_F / KS;       // 64 k per block
constexpr int IT = 16;              // k chunk in LDS
constexpr int PITCH = IT + 4;       // f32 rows: 16B-aligned, 2-way banks (free)
constexpr int HP = IT + 4;          // f16 rows: 40B stride, conflict-free b64
constexpr int LP = OT + 1;          // epilogue merge pitch
constexpr int NCH = KR / IT;        // 4 chunks
constexpr int BO  = BATCH * OUT_F;  // 524288

#define LOG2E 1.44269504088897f
#define C2f   (-0.72134752044448f)
#define NC2f  ( 0.72134752044448f)
#define RQf   (-0.84083003f)   /* 2^C2 / C2 = e^{-1/2}/C2 */

typedef float v2f   __attribute__((ext_vector_type(2)));
typedef float f32x4 __attribute__((ext_vector_type(4)));
typedef _Float16 half4 __attribute__((ext_vector_type(4)));

__device__ __forceinline__ float fexp2(float v) { return __builtin_amdgcn_exp2f(v); }
__device__ __forceinline__ float frcp(float v)  { return __builtin_amdgcn_rcpf(v); }
__device__ __forceinline__ v2f pkfma(v2f a, v2f b, v2f c) {
  return __builtin_elementwise_fma(a, b, c);
}
__device__ __forceinline__ float fsilu(float v) {
  return v * frcp(1.f + fexp2(v * -LOG2E));
}

// LDS carve (floats):
//   lx   [   0..1279]  x tile, f32, 64x20
//   la   [1280..2559]  lm [2560..3839]  ln [3840..5119]  lq [5120..6399]
//   hx   [6400..7039]  silu(x) f16 64x20 (MFMA A)
//   hb   [7040..7679]  basew   f16 64x20 (MFMA B)
//   lout [   0..4159]  ALIAS of lx/la/lm/ln: epilogue merge 64x65 (after barrier)
constexpr int SMEM_F = 7680;        // 30720 B

__global__ __launch_bounds__(256, 2)
void wkan_main(const float* __restrict__ x, const float* __restrict__ basew,
               const float* __restrict__ wavew, const float* __restrict__ scale,
               const float* __restrict__ transl, const float* __restrict__ bias,
               float* __restrict__ partial, float* __restrict__ out, int use_ws)
{
  __shared__ float smem[SMEM_F];
  float* lx = smem;
  float* la = smem + 1280;
  float* lm = smem + 2560;
  float* ln = smem + 3840;
  float* lq = smem + 5120;
  _Float16* hx = (_Float16*)(smem + 6400);
  _Float16* hb = (_Float16*)(smem + 7040);
  float* lout = smem;               // epilogue alias

  const int tid = threadIdx.x;
  const int b0 = blockIdx.x * BT;
  const int o0 = blockIdx.y * OT;
  const int ks = blockIdx.z;
  const int k0 = ks * KR;

  const int srow = tid >> 2;        // 0..63 staging row
  const int sc4  = (tid & 3) * 4;   // 0,4,8,12
  const int lofs = srow * PITCH + sc4;
  const int hofs = srow * HP + sc4;

  const int to = tid & 15;          // output col group (cols to + 16c)
  const int tb = tid >> 4;          // output row group 0..15 (rows tb + 16r)

  const int lane = tid & 63;
  const int wid  = tid >> 6;        // wave 0..3 -> m-tile wid
  const int frow = lane & 15;       // m/n within MFMA tile
  const int kgrp = (lane >> 4) * 4; // k group within chunk

  v2f zz; zz.x = 0.f; zz.y = 0.f;
  v2f acc[4][4];
#pragma unroll
  for (int r = 0; r < 4; ++r)
#pragma unroll
    for (int c = 0; c < 4; ++c) acc[r][c] = zz;

  f32x4 accb[4];                    // base-GEMM fragments: 4 n-tiles
#pragma unroll
  for (int nt = 0; nt < 4; ++nt) accb[nt] = (f32x4)0.f;

  for (int kc = 0; kc < NCH; ++kc) {
    const int g = k0 + kc * IT + sc4;
    if (kc) __syncthreads();          // prev-chunk readers done
    // ---------- stage chunk (direct loads; TLP hides latency at 4 blk/CU) --
    {
      float4 xv = *(const float4*)(x + (size_t)(b0 + srow) * IN_F + g);
      float4 sx;
      sx.x = fsilu(xv.x); sx.y = fsilu(xv.y); sx.z = fsilu(xv.z); sx.w = fsilu(xv.w);
      *(float4*)(lx + lofs) = xv;
      half4 h0;
      h0[0] = (_Float16)sx.x; h0[1] = (_Float16)sx.y;
      h0[2] = (_Float16)sx.z; h0[3] = (_Float16)sx.w;
      *(half4*)(hx + hofs) = h0;

      float4 sv = *(const float4*)(scale  + (size_t)(o0 + srow) * IN_F + g);
      float4 tv = *(const float4*)(transl + (size_t)(o0 + srow) * IN_F + g);
      float4 av, mv, nv;
      {
        float a2, a2t;
        a2 = C2f * frcp(sv.x * sv.x); a2t = a2 * tv.x;
        av.x = a2; mv.x = -2.f * a2t; nv.x = fmaf(a2t, tv.x, NC2f);
        a2 = C2f * frcp(sv.y * sv.y); a2t = a2 * tv.y;
        av.y = a2; mv.y = -2.f * a2t; nv.y = fmaf(a2t, tv.y, NC2f);
        a2 = C2f * frcp(sv.z * sv.z); a2t = a2 * tv.z;
        av.z = a2; mv.z = -2.f * a2t; nv.z = fmaf(a2t, tv.z, NC2f);
        a2 = C2f * frcp(sv.w * sv.w); a2t = a2 * tv.w;
        av.w = a2; mv.w = -2.f * a2t; nv.w = fmaf(a2t, tv.w, NC2f);
      }
      *(float4*)(la + lofs) = av;
      *(float4*)(lm + lofs) = mv;
      *(float4*)(ln + lofs) = nv;

      float4 wv = *(const float4*)(wavew + (size_t)(o0 + srow) * IN_F + g);
      float4 qv;
      qv.x = wv.x * RQf; qv.y = wv.y * RQf; qv.z = wv.z * RQf; qv.w = wv.w * RQf;
      *(float4*)(lq + lofs) = qv;

      float4 bv = *(const float4*)(basew + (size_t)(o0 + srow) * IN_F + g);
      half4 hbv;
      hbv[0] = (_Float16)bv.x; hbv[1] = (_Float16)bv.y;
      hbv[2] = (_Float16)bv.z; hbv[3] = (_Float16)bv.w;
      *(half4*)(hb + hofs) = hbv;
    }
    __syncthreads();                  // chunk kc ready in LDS

    // ---------- base branch: 4 MFMA on the matrix pipe ----------
    {
      half4 af = *(const half4*)(hx + (wid * 16 + frow) * HP + kgrp);
#pragma unroll
      for (int nt = 0; nt < 4; ++nt) {
        half4 bf = *(const half4*)(hb + (nt * 16 + frow) * HP + kgrp);
        accb[nt] = __builtin_amdgcn_mfma_f32_16x16x16f16(af, bf, accb[nt], 0, 0, 0);
      }
    }

    // ---------- wavelet: 4x4 outputs/thread on the VALU (Horner) ----------
    for (int ii = 0; ii < IT; ii += 4) {
      float4 xr[4];
#pragma unroll
      for (int r = 0; r < 4; ++r) {
        const int row = (tb + 16 * r) * PITCH + ii;
        xr[r] = *(const float4*)(lx + row);
      }
#pragma unroll
      for (int c = 0; c < 4; ++c) {
        const int orow = (to + 16 * c) * PITCH + ii;
        float4 A = *(const float4*)(la + orow);
        float4 M = *(const float4*)(lm + orow);
        float4 N = *(const float4*)(ln + orow);
        float4 Q = *(const float4*)(lq + orow);
        v2f Al = {A.x, A.y}, Ah = {A.z, A.w};
        v2f Ml = {M.x, M.y}, Mh = {M.z, M.w};
        v2f Nl = {N.x, N.y}, Nh = {N.z, N.w};
        v2f Ql = {Q.x, Q.y}, Qh = {Q.z, Q.w};
#pragma unroll
        for (int r = 0; r < 4; ++r) {
          v2f xl  = {xr[r].x, xr[r].y}, xh  = {xr[r].z, xr[r].w};
          v2f p, e, gg;
          p = pkfma(pkfma(Al, xl, Ml), xl, Nl);
          e.x = fexp2(p.x); e.y = fexp2(p.y);
          gg = p * Ql;
          acc[r][c] = pkfma(gg, e, acc[r][c]);
          p = pkfma(pkfma(Ah, xh, Mh), xh, Nh);
          e.x = fexp2(p.x); e.y = fexp2(p.y);
          gg = p * Qh;
          acc[r][c] = pkfma(gg, e, acc[r][c]);
        }
      }
    }
  }

  // ---------- epilogue: merge base fragments with wavelet acc ----------
  __syncthreads();                  // all LDS tile reads done; lout may alias
  // D layout: n = lane&15, m = (lane>>4)*4 + i   (within each 16x16 tile)
#pragma unroll
  for (int nt = 0; nt < 4; ++nt)
#pragma unroll
    for (int i = 0; i < 4; ++i)
      lout[(wid * 16 + (lane >> 4) * 4 + i) * LP + nt * 16 + frow] = accb[nt][i];
  __syncthreads();

#pragma unroll
  for (int r = 0; r < 4; ++r) {
    const int br = b0 + tb + 16 * r;
#pragma unroll
    for (int c = 0; c < 4; ++c) {
      const int oc = o0 + to + 16 * c;
      float res = acc[r][c].x + acc[r][c].y
                + lout[(tb + 16 * r) * LP + to + 16 * c];
      if (use_ws) {
        partial[(size_t)ks * BO + (size_t)br * OUT_F + oc] = res;
      } else {
        if (ks == 0) res += bias[oc];
        atomicAdd(out + (size_t)br * OUT_F + oc, res);
      }
    }
  }
}

__global__ __launch_bounds__(256)
void wkan_reduce(const float* __restrict__ partial, const float* __restrict__ bias,
                 float* __restrict__ out)
{
  const int i4 = (blockIdx.x * 256 + threadIdx.x) * 4;
  float4 r = *(const float4*)(bias + (i4 & (OUT_F - 1)));
#pragma unroll
  for (int k = 0; k < KS; ++k) {
    float4 a = *(const float4*)(partial + (size_t)k * BO + i4);
    r.x += a.x; r.y += a.y; r.z += a.z; r.w += a.w;
  }
  *(float4*)(out + i4) = r;
}

extern "C" void kernel_launch(void* const* d_in, const int* in_sizes, int n_in,
                              void* d_out, int out_size, void* d_ws, size_t ws_size,
                              hipStream_t stream) {
  const float* x  = (const float*)d_in[0];
  const float* bw = (const float*)d_in[1];
  const float* ww = (const float*)d_in[2];
  const float* sc = (const float*)d_in[3];
  const float* tr = (const float*)d_in[4];
  const float* bi = (const float*)d_in[5];
  float* out = (float*)d_out;

  const int use_ws = ws_size >= (size_t)KS * BO * sizeof(float) ? 1 : 0;
  if (!use_ws) {
    hipMemsetAsync(d_out, 0, (size_t)out_size * sizeof(float), stream);
  }
  dim3 grid(BATCH / BT, OUT_F / OT, KS);  // 16 x 8 x 8 = 1024 blocks, 4/CU
  wkan_main<<<grid, dim3(256), 0, stream>>>(x, bw, ww, sc, tr, bi,
                                            (float*)d_ws, out, use_ws);
  if (use_ws) {
    wkan_reduce<<<dim3(BO / 1024), dim3(256), 0, stream>>>((const float*)d_ws, bi, out);
  }
}